// Round 2
// baseline (571.971 us; speedup 1.0000x reference)
//
#include <hip/hip_runtime.h>

typedef unsigned short u16;
typedef unsigned int   u32;
typedef __attribute__((ext_vector_type(4))) float f32x4;
typedef __attribute__((ext_vector_type(4))) int   i32x4;
typedef __attribute__((ext_vector_type(4))) u32   u32x4;

#define NPAIR 32768   // B*H
#define NB    25
#define FD    128
#define TILEB 13312   // LDS slot stride: 26 rows * 512 B (fp32 tile); bf16 tile uses first 6656 B

__device__ __forceinline__ float bflo(u32 u){ return __uint_as_float(u << 16); }
__device__ __forceinline__ float bfhi(u32 u){ return __uint_as_float(u & 0xFFFF0000u); }
__device__ __forceinline__ u16 f2bf(float f){
  u32 u = __float_as_uint(f);
  u += 0x7FFFu + ((u >> 16) & 1u);   // RNE
  return (u16)(u >> 16);
}
// sum across each 16-lane row (masks 1..8 stay within the row)
__device__ __forceinline__ float rowsum16(float x){
  x += __shfl_xor(x, 1);
  x += __shfl_xor(x, 2);
  x += __shfl_xor(x, 4);
  x += __shfl_xor(x, 8);
  return x;
}
// dtype sniff: fp32 data has random-exponent garbage in low u16 halves
__device__ __forceinline__ bool sniff_f32(const u16* __restrict__ xsniff, int l){
  const u16 v1 = xsniff[l], v2 = xsniff[64 + l];
  int e1 = (v1 >> 7) & 0xFF, e2 = (v2 >> 7) & 0xFF;
  int e = e1 > e2 ? e1 : e2;
  #pragma unroll
  for (int m = 1; m <= 32; m <<= 1){ int o = __shfl_xor(e, m); e = e > o ? e : o; }
  unsigned long long zb = __ballot(((l & 1) == 0) && (v1 == 0 || v2 == 0));
  return (e >= 141) || (__popcll(zb) >= 20);
}

// ---- direct global->LDS DMA (LDS dest = wave-uniform base + lane*size; global src per-lane)
__device__ __forceinline__ void gld16(const void* g, void* l){
  __builtin_amdgcn_global_load_lds((const __attribute__((address_space(1))) u32*)g,
                                   (__attribute__((address_space(3))) u32*)l, 16, 0, 0);
}
__device__ __forceinline__ void gld4(const void* g, void* l){
  __builtin_amdgcn_global_load_lds((const __attribute__((address_space(1))) u32*)g,
                                   (__attribute__((address_space(3))) u32*)l, 4, 0, 0);
}
template<int N> __device__ __forceinline__ void wait_vmcnt(){
  if constexpr (N == 0)  asm volatile("s_waitcnt vmcnt(0)"  ::: "memory");
  if constexpr (N == 8)  asm volatile("s_waitcnt vmcnt(8)"  ::: "memory");
  if constexpr (N == 13) asm volatile("s_waitcnt vmcnt(13)" ::: "memory");
  __builtin_amdgcn_sched_barrier(0);
}

// stage one pair tile (x_self row + 25 x_neigh rows, raw dtype) into an LDS slot.
// fp32: 13 x 1024B chunks (13 vmcnt ops). bf16: 6 x 1024B + 2 x 256B (8 vmcnt ops).
template<bool FP32>
__device__ __forceinline__ void stage_pair(const char* xs, const char* xn, int p, char* slot, int lane){
  if constexpr (FP32){
    #pragma unroll
    for (int c = 0; c < 13; ++c){
      const int o = c*1024 + lane*16;
      const char* src = (o < 512) ? (xs + (size_t)p*512   + o)
                                  : (xn + (size_t)p*12800 + (o - 512));
      gld16(src, slot + c*1024);
    }
  } else {
    #pragma unroll
    for (int c = 0; c < 6; ++c){
      const int o = c*1024 + lane*16;
      const char* src = (o < 256) ? (xs + (size_t)p*256  + o)
                                  : (xn + (size_t)p*6400 + (o - 256));
      gld16(src, slot + c*1024);
    }
    #pragma unroll
    for (int c = 0; c < 2; ++c){
      const int o = 6144 + c*256 + lane*4;
      const char* src = xn + (size_t)p*6400 + (o - 256);
      gld4(src, slot + 6144 + c*256);
    }
  }
}

// ---------------- Kernel A: wa = [W@a_self | W@a_neigh] (blocks 0..127)
//                  + W packed into MFMA B-fragment order, bf16 (blocks 128..159)
__global__ __launch_bounds__(64) void prep(const void* w_, const void* as_, const void* an_,
                                           const u16* __restrict__ xsniff,
                                           float* __restrict__ wa, u16* __restrict__ wpk,
                                           int* __restrict__ flag_out){
  const int l = threadIdx.x;
  const bool isf32 = sniff_f32(xsniff, l);

  if (blockIdx.x < FD){
    const int f = blockIdx.x;
    float ps, pn;
    if (isf32){
      const float* w  = (const float*)w_;
      const float* as = (const float*)as_;
      const float* an = (const float*)an_;
      float w0 = w[f*FD + 2*l], w1 = w[f*FD + 2*l + 1];
      ps = w0*as[2*l] + w1*as[2*l+1];
      pn = w0*an[2*l] + w1*an[2*l+1];
    } else {
      const u16* w  = (const u16*)w_;
      const u16* as = (const u16*)as_;
      const u16* an = (const u16*)an_;
      u32 wd = *(const u32*)(w + f*FD + 2*l);
      u32 av = *(const u32*)(as + 2*l);
      u32 nv = *(const u32*)(an + 2*l);
      ps = bflo(wd)*bflo(av) + bfhi(wd)*bfhi(av);
      pn = bflo(wd)*bflo(nv) + bfhi(wd)*bfhi(nv);
    }
    #pragma unroll
    for(int m=1; m<=32; m<<=1){ ps += __shfl_xor(ps, m); pn += __shfl_xor(pn, m); }
    if (l == 0){ wa[f] = ps; wa[FD + f] = pn; }
    if (blockIdx.x == 0 && l == 0) flag_out[0] = isf32 ? 1 : 0;
  } else {
    // pack B fragments: unit = ((nt*4 + kt)*64 + lane); 8 u16 each
    const int unit = (blockIdx.x - FD)*64 + l;        // 0..2047
    const int nt   = unit >> 8;
    const int kt   = (unit >> 6) & 3;
    const int fl   = unit & 63;
    const int col  = fl & 15, quad = fl >> 4;
    union { u16 s[8]; u32x4 u; } bb;
    #pragma unroll
    for (int j = 0; j < 8; ++j){
      const int idx = (kt*32 + quad*8 + j)*FD + nt*16 + col;
      bb.s[j] = isf32 ? f2bf(((const float*)w_)[idx]) : ((const u16*)w_)[idx];
    }
    *(u32x4*)(wpk + unit*8) = bb.u;
  }
}

// ---------------- Fused kernel: per block = 16 (b,h) pairs, 4 waves.
// Phase 1: per-wave double-buffered global_load_lds staging of pair tiles;
//          attention-weighted xbar -> LDS (bf16), counted-vmcnt pipeline.
// Phase 2: out[16][128] = relu(xbar @ W) via MFMA, B-fragments preloaded from packed W.
template<bool FP32>
__device__ __forceinline__ void fused_body(const void* __restrict__ xs_, const void* __restrict__ xn_,
                                           const float* __restrict__ wa, const u16* __restrict__ wpk,
                                           void* __restrict__ out_, char* stg, u16* xb){
  const int tid  = threadIdx.x;
  const int lane = tid & 63, wv = tid >> 6;
  const int g  = lane >> 4;      // row-group: vector v = 4*i + g
  const int q  = lane & 15;      // feature lane: f = 8q..8q+7
  const int f0 = q << 3;
  const int pbase = blockIdx.x * 16;
  const int p0    = pbase + wv*4;
  const char* xs = (const char*)xs_;
  const char* xn = (const char*)xn_;

  float was[8], wan[8];
  {
    f32x4 a = *(const f32x4*)(wa + f0);
    f32x4 b = *(const f32x4*)(wa + f0 + 4);
    was[0]=a[0]; was[1]=a[1]; was[2]=a[2]; was[3]=a[3];
    was[4]=b[0]; was[5]=b[1]; was[6]=b[2]; was[7]=b[3];
    f32x4 c = *(const f32x4*)(wa + FD + f0);
    f32x4 d = *(const f32x4*)(wa + FD + f0 + 4);
    wan[0]=c[0]; wan[1]=c[1]; wan[2]=c[2]; wan[3]=c[3];
    wan[4]=d[0]; wan[5]=d[1]; wan[6]=d[2]; wan[7]=d[3];
  }

  // Phase-2 B fragments: issue now, they complete while we stream x (L2-hot, 8 loads).
  i32x4 bfru[2][4];
  #pragma unroll
  for (int ntl = 0; ntl < 2; ++ntl)
    #pragma unroll
    for (int kt = 0; kt < 4; ++kt)
      bfru[ntl][kt] = *(const i32x4*)(wpk + (size_t)(((wv*2 + ntl)*4 + kt)*64 + lane)*8);

  char* slot0 = stg + (size_t)wv*TILEB;        // buffer 0, this wave's slot
  char* slot1 = stg + (size_t)(4 + wv)*TILEB;  // buffer 1, this wave's slot
  stage_pair<FP32>(xs, xn, p0, slot0, lane);   // prologue: pair 0 in flight

  #pragma unroll
  for (int pp = 0; pp < 4; ++pp){
    char* cur = (pp & 1) ? slot1 : slot0;
    char* nxt = (pp & 1) ? slot0 : slot1;
    if (pp < 3){
      stage_pair<FP32>(xs, xn, p0 + pp + 1, nxt, lane);  // keep next tile streaming
      wait_vmcnt<(FP32 ? 13 : 8)>();                     // current tile complete; next stays in flight
    } else {
      wait_vmcnt<0>();
    }

    // ---- attention for pair p0+pp from LDS tile `cur` (identical math to verified version)
    float xf[7][8];
    #pragma unroll
    for(int i=0;i<7;++i){
      const int v = 4*i + g;
      if (v <= NB){
        if constexpr (FP32){
          const char* rp = cur + v*512 + f0*4;
          f32x4 A = *(const f32x4*)rp;
          f32x4 B = *(const f32x4*)(rp + 16);
          xf[i][0]=A[0]; xf[i][1]=A[1]; xf[i][2]=A[2]; xf[i][3]=A[3];
          xf[i][4]=B[0]; xf[i][5]=B[1]; xf[i][6]=B[2]; xf[i][7]=B[3];
        } else {
          const char* rp = cur + v*256 + f0*2;
          u32x4 d = *(const u32x4*)rp;
          xf[i][0]=bflo(d[0]); xf[i][1]=bfhi(d[0]);
          xf[i][2]=bflo(d[1]); xf[i][3]=bfhi(d[1]);
          xf[i][4]=bflo(d[2]); xf[i][5]=bfhi(d[2]);
          xf[i][6]=bflo(d[3]); xf[i][7]=bfhi(d[3]);
        }
      } else {
        #pragma unroll
        for(int j=0;j<8;++j) xf[i][j] = 0.f;
      }
    }

    float pn[7];
    #pragma unroll
    for(int i=0;i<7;++i){
      float s = 0.f;
      #pragma unroll
      for(int j=0;j<8;++j) s += xf[i][j]*wan[j];
      pn[i] = rowsum16(s);
    }
    float ps = 0.f;
    #pragma unroll
    for(int j=0;j<8;++j) ps += xf[0][j]*was[j];
    ps = rowsum16(ps);
    const float s_self = __shfl(ps, 0);   // row 0 holds x_self . wa_self

    float u[7];
    #pragma unroll
    for(int i=0;i<7;++i){
      const int v = 4*i + g;
      if (v <= NB){
        float t = s_self + pn[i];
        u[i] = fmaxf(t, 0.2f*t);          // leaky_relu(0.2)
      } else u[i] = -3.0e38f;
    }
    float m = u[0];
    #pragma unroll
    for(int i=1;i<7;++i) m = fmaxf(m, u[i]);
    m = fmaxf(m, __shfl_xor(m, 16));
    m = fmaxf(m, __shfl_xor(m, 32));

    float e[7]; float S = 0.f;
    #pragma unroll
    for(int i=0;i<7;++i){
      const int v = 4*i + g;
      e[i] = (v <= NB) ? __expf(u[i] - m) : 0.f;
      S += e[i];
    }
    S += __shfl_xor(S, 16);
    S += __shfl_xor(S, 32);
    const float rinv = 1.0f / S;

    float acc[8];
    #pragma unroll
    for(int j=0;j<8;++j) acc[j] = 0.f;
    #pragma unroll
    for(int i=0;i<7;++i)
      #pragma unroll
      for(int j=0;j<8;++j) acc[j] += e[i]*xf[i][j];
    #pragma unroll
    for(int j=0;j<8;++j){
      acc[j] += __shfl_xor(acc[j], 16);
      acc[j] += __shfl_xor(acc[j], 32);
      acc[j] *= rinv;
    }
    if (g == 0){
      const int row = wv*4 + pp;
      u32 o0 = (u32)f2bf(acc[0]) | ((u32)f2bf(acc[1])<<16);
      u32 o1 = (u32)f2bf(acc[2]) | ((u32)f2bf(acc[3])<<16);
      u32 o2 = (u32)f2bf(acc[4]) | ((u32)f2bf(acc[5])<<16);
      u32 o3 = (u32)f2bf(acc[6]) | ((u32)f2bf(acc[7])<<16);
      u32x4 ov = {o0, o1, o2, o3};
      *(u32x4*)(xb + row*FD + f0) = ov;
    }
  }
  __syncthreads();

  // ---- Phase 2: MFMA matvec. wave wv owns output columns [wv*32, wv*32+32).
  const int col = q, quad = g;
  f32x4 acc2[2];
  { f32x4 z = {0.f,0.f,0.f,0.f}; acc2[0] = z; acc2[1] = z; }
  #pragma unroll
  for (int kt = 0; kt < 4; ++kt){
    i32x4 av = *(const i32x4*)(xb + col*FD + kt*32 + quad*8);  // A[m=col][k]
    #pragma unroll
    for (int ntl = 0; ntl < 2; ++ntl){
      // s_nop 1: VALU-write -> MFMA-read SrcA/B hazard; trailing nops: MFMA-write -> VALU-read
      asm volatile("s_nop 1\n\t"
                   "v_mfma_f32_16x16x32_bf16 %0, %1, %2, %0\n\t"
                   "s_nop 7\n\t"
                   "s_nop 7"
                   : "+v"(acc2[ntl]) : "v"(av), "v"(bfru[ntl][kt]));
    }
  }
  if (FP32){
    float* o = (float*)out_;
    #pragma unroll
    for (int ntl = 0; ntl < 2; ++ntl){
      const int n0 = (wv*2 + ntl)*16 + col;
      #pragma unroll
      for (int r = 0; r < 4; ++r)
        o[(size_t)(pbase + quad*4 + r)*FD + n0] = fmaxf(acc2[ntl][r], 0.f);
    }
  } else {
    u16* o = (u16*)out_;
    #pragma unroll
    for (int ntl = 0; ntl < 2; ++ntl){
      const int n0 = (wv*2 + ntl)*16 + col;
      #pragma unroll
      for (int r = 0; r < 4; ++r)
        o[(size_t)(pbase + quad*4 + r)*FD + n0] = f2bf(fmaxf(acc2[ntl][r], 0.f));
    }
  }
}

__global__ __launch_bounds__(256, 1) void fused(const void* __restrict__ xs, const void* __restrict__ xn,
                                                const float* __restrict__ wa, const int* __restrict__ flag,
                                                const u16* __restrict__ wpk, void* __restrict__ out_){
  __shared__ __align__(16) char stg[8*TILEB];   // 104 KiB: 2 buffers x 4 wave-slots x 13 KiB tile
  __shared__ __align__(16) u16  xb[16*FD];      // 4 KiB: 16 xbar rows, bf16
  if (flag[0]) fused_body<true >(xs, xn, wa, wpk, out_, stg, xb);
  else         fused_body<false>(xs, xn, wa, wpk, out_, stg, xb);
}

extern "C" void kernel_launch(void* const* d_in, const int* in_sizes, int n_in,
                              void* d_out, int out_size, void* d_ws, size_t ws_size,
                              hipStream_t stream){
  const void* x_self  = d_in[0];
  const void* x_neigh = d_in[1];
  const void* w_feat  = d_in[2];
  const void* a_self  = d_in[3];
  const void* a_neigh = d_in[4];

  int*   flag = (int*)d_ws;                  // byte 0
  float* wa   = (float*)d_ws + 64;           // byte 256: 256 floats [wa_self | wa_neigh]
  u16*   wpk  = (u16*)d_ws + 1024;           // byte 2048: 2048 fragments x 8 u16 = 32 KB packed W

  prep <<<FD + 32,  64, 0, stream>>>(w_feat, a_self, a_neigh, (const u16*)x_self, wa, wpk, flag);
  fused<<<NPAIR/16, 256, 0, stream>>>(x_self, x_neigh, wa, flag, wpk, d_out);
}

// Round 3
// 542.810 us; speedup vs baseline: 1.0537x; 1.0537x over previous
//
#include <hip/hip_runtime.h>

typedef unsigned short u16;
typedef unsigned int   u32;
typedef __attribute__((ext_vector_type(4))) float f32x4;
typedef __attribute__((ext_vector_type(4))) int   i32x4;
typedef __attribute__((ext_vector_type(4))) u32   u32x4;

#define NPAIR 32768   // B*H
#define NB    25
#define FD    128

__device__ __forceinline__ float bflo(u32 u){ return __uint_as_float(u << 16); }
__device__ __forceinline__ float bfhi(u32 u){ return __uint_as_float(u & 0xFFFF0000u); }
__device__ __forceinline__ u16 f2bf(float f){
  u32 u = __float_as_uint(f);
  u += 0x7FFFu + ((u >> 16) & 1u);   // RNE
  return (u16)(u >> 16);
}
// sum across each 16-lane row (masks 1..8 stay within the row)
__device__ __forceinline__ float rowsum16(float x){
  x += __shfl_xor(x, 1);
  x += __shfl_xor(x, 2);
  x += __shfl_xor(x, 4);
  x += __shfl_xor(x, 8);
  return x;
}
// dtype sniff: fp32 data has random-exponent garbage in low u16 halves
__device__ __forceinline__ bool sniff_f32(const u16* __restrict__ xsniff, int l){
  const u16 v1 = xsniff[l], v2 = xsniff[64 + l];
  int e1 = (v1 >> 7) & 0xFF, e2 = (v2 >> 7) & 0xFF;
  int e = e1 > e2 ? e1 : e2;
  #pragma unroll
  for (int m = 1; m <= 32; m <<= 1){ int o = __shfl_xor(e, m); e = e > o ? e : o; }
  unsigned long long zb = __ballot(((l & 1) == 0) && (v1 == 0 || v2 == 0));
  return (e >= 141) || (__popcll(zb) >= 20);
}

// ---------------- Kernel A: wa = [W@a_self | W@a_neigh] (blocks 0..127)
//                  + W packed into MFMA B-fragment order, bf16 (blocks 128..159)
__global__ __launch_bounds__(64) void prep(const void* w_, const void* as_, const void* an_,
                                           const u16* __restrict__ xsniff,
                                           float* __restrict__ wa, u16* __restrict__ wpk,
                                           int* __restrict__ flag_out){
  const int l = threadIdx.x;
  const bool isf32 = sniff_f32(xsniff, l);

  if (blockIdx.x < FD){
    const int f = blockIdx.x;
    float ps, pn;
    if (isf32){
      const float* w  = (const float*)w_;
      const float* as = (const float*)as_;
      const float* an = (const float*)an_;
      float w0 = w[f*FD + 2*l], w1 = w[f*FD + 2*l + 1];
      ps = w0*as[2*l] + w1*as[2*l+1];
      pn = w0*an[2*l] + w1*an[2*l+1];
    } else {
      const u16* w  = (const u16*)w_;
      const u16* as = (const u16*)as_;
      const u16* an = (const u16*)an_;
      u32 wd = *(const u32*)(w + f*FD + 2*l);
      u32 av = *(const u32*)(as + 2*l);
      u32 nv = *(const u32*)(an + 2*l);
      ps = bflo(wd)*bflo(av) + bfhi(wd)*bfhi(av);
      pn = bflo(wd)*bflo(nv) + bfhi(wd)*bfhi(nv);
    }
    #pragma unroll
    for(int m=1; m<=32; m<<=1){ ps += __shfl_xor(ps, m); pn += __shfl_xor(pn, m); }
    if (l == 0){ wa[f] = ps; wa[FD + f] = pn; }
    if (blockIdx.x == 0 && l == 0) flag_out[0] = isf32 ? 1 : 0;
  } else {
    // pack B fragments: unit = ((nt*4 + kt)*64 + lane); 8 u16 each
    const int unit = (blockIdx.x - FD)*64 + l;        // 0..2047
    const int nt   = unit >> 8;
    const int kt   = (unit >> 6) & 3;
    const int fl   = unit & 63;
    const int col  = fl & 15, quad = fl >> 4;
    union { u16 s[8]; u32x4 u; } bb;
    #pragma unroll
    for (int j = 0; j < 8; ++j){
      const int idx = (kt*32 + quad*8 + j)*FD + nt*16 + col;
      bb.s[j] = isf32 ? f2bf(((const float*)w_)[idx]) : ((const u16*)w_)[idx];
    }
    *(u32x4*)(wpk + unit*8) = bb.u;
  }
}

// ---------------- Fused kernel: per block = 16 (b,h) pairs.
// Phase 1: each wave computes attention-weighted xbar for 4 pairs -> LDS (bf16).
// Phase 2: out[16][128] = relu(xbar @ W) via MFMA, B-fragments from packed W.
template<bool FP32>
__device__ __forceinline__ void fused_body(const void* __restrict__ xs_, const void* __restrict__ xn_,
                                           const float* __restrict__ wa, const u16* __restrict__ wpk,
                                           void* __restrict__ out_, u16* __restrict__ xb){
  const int tid  = threadIdx.x;
  const int lane = tid & 63, wv = tid >> 6;
  const int g  = lane >> 4;      // row-group: vector v = 4*i + g
  const int q  = lane & 15;      // feature lane: f = 8q..8q+7
  const int f0 = q << 3;
  const int pbase = blockIdx.x * 16;

  float was[8], wan[8];
  {
    f32x4 a = *(const f32x4*)(wa + f0);
    f32x4 b = *(const f32x4*)(wa + f0 + 4);
    was[0]=a[0]; was[1]=a[1]; was[2]=a[2]; was[3]=a[3];
    was[4]=b[0]; was[5]=b[1]; was[6]=b[2]; was[7]=b[3];
    f32x4 c = *(const f32x4*)(wa + FD + f0);
    f32x4 d = *(const f32x4*)(wa + FD + f0 + 4);
    wan[0]=c[0]; wan[1]=c[1]; wan[2]=c[2]; wan[3]=c[3];
    wan[4]=d[0]; wan[5]=d[1]; wan[6]=d[2]; wan[7]=d[3];
  }

  #pragma unroll 1            // keep VGPRs low; TLP across waves hides latency
  for (int pp = 0; pp < 4; ++pp){
    const int row = wv*4 + pp;     // local xbar row 0..15
    const int p   = pbase + row;   // global pair

    float xf[7][8];
    #pragma unroll
    for(int i=0;i<7;++i){
      const int v = 4*i + g;
      if (v <= NB){
        if (FP32){
          const float* src = (v==0) ? ((const float*)xs_ + (size_t)p*FD + f0)
                                    : ((const float*)xn_ + (size_t)p*(NB*FD) + (size_t)(v-1)*FD + f0);
          f32x4 A = __builtin_nontemporal_load((const f32x4*)src);
          f32x4 B = __builtin_nontemporal_load((const f32x4*)(src + 4));
          xf[i][0]=A[0]; xf[i][1]=A[1]; xf[i][2]=A[2]; xf[i][3]=A[3];
          xf[i][4]=B[0]; xf[i][5]=B[1]; xf[i][6]=B[2]; xf[i][7]=B[3];
        } else {
          const u16* src = (v==0) ? ((const u16*)xs_ + (size_t)p*FD + f0)
                                  : ((const u16*)xn_ + (size_t)p*(NB*FD) + (size_t)(v-1)*FD + f0);
          u32x4 d = __builtin_nontemporal_load((const u32x4*)src);
          xf[i][0]=bflo(d[0]); xf[i][1]=bfhi(d[0]);
          xf[i][2]=bflo(d[1]); xf[i][3]=bfhi(d[1]);
          xf[i][4]=bflo(d[2]); xf[i][5]=bfhi(d[2]);
          xf[i][6]=bflo(d[3]); xf[i][7]=bfhi(d[3]);
        }
      } else {
        #pragma unroll
        for(int j=0;j<8;++j) xf[i][j] = 0.f;
      }
    }

    float pn[7];
    #pragma unroll
    for(int i=0;i<7;++i){
      float s = 0.f;
      #pragma unroll
      for(int j=0;j<8;++j) s += xf[i][j]*wan[j];
      pn[i] = rowsum16(s);
    }
    float ps = 0.f;
    #pragma unroll
    for(int j=0;j<8;++j) ps += xf[0][j]*was[j];
    ps = rowsum16(ps);
    const float s_self = __shfl(ps, 0);   // row 0 holds x_self . wa_self

    float u[7];
    #pragma unroll
    for(int i=0;i<7;++i){
      const int v = 4*i + g;
      if (v <= NB){
        float t = s_self + pn[i];
        u[i] = fmaxf(t, 0.2f*t);          // leaky_relu(0.2)
      } else u[i] = -3.0e38f;
    }
    float m = u[0];
    #pragma unroll
    for(int i=1;i<7;++i) m = fmaxf(m, u[i]);
    m = fmaxf(m, __shfl_xor(m, 16));
    m = fmaxf(m, __shfl_xor(m, 32));

    float e[7]; float S = 0.f;
    #pragma unroll
    for(int i=0;i<7;++i){
      const int v = 4*i + g;
      e[i] = (v <= NB) ? __expf(u[i] - m) : 0.f;
      S += e[i];
    }
    S += __shfl_xor(S, 16);
    S += __shfl_xor(S, 32);
    const float rinv = 1.0f / S;

    float acc[8];
    #pragma unroll
    for(int j=0;j<8;++j) acc[j] = 0.f;
    #pragma unroll
    for(int i=0;i<7;++i)
      #pragma unroll
      for(int j=0;j<8;++j) acc[j] += e[i]*xf[i][j];
    #pragma unroll
    for(int j=0;j<8;++j){
      acc[j] += __shfl_xor(acc[j], 16);
      acc[j] += __shfl_xor(acc[j], 32);
      acc[j] *= rinv;
    }
    if (g == 0){
      u32 o0 = (u32)f2bf(acc[0]) | ((u32)f2bf(acc[1])<<16);
      u32 o1 = (u32)f2bf(acc[2]) | ((u32)f2bf(acc[3])<<16);
      u32 o2 = (u32)f2bf(acc[4]) | ((u32)f2bf(acc[5])<<16);
      u32 o3 = (u32)f2bf(acc[6]) | ((u32)f2bf(acc[7])<<16);
      u32x4 ov = {o0, o1, o2, o3};
      *(u32x4*)(xb + row*FD + f0) = ov;
    }
  }
  __syncthreads();

  // ---- Phase 2: MFMA matvec. wave wv owns output columns [wv*32, wv*32+32).
  const int col = q, quad = g;
  i32x4 bfru[2][4];
  #pragma unroll
  for (int ntl = 0; ntl < 2; ++ntl)
    #pragma unroll
    for (int kt = 0; kt < 4; ++kt)
      bfru[ntl][kt] = *(const i32x4*)(wpk + (size_t)(((wv*2 + ntl)*4 + kt)*64 + lane)*8);

  f32x4 acc2[2];
  { f32x4 z = {0.f,0.f,0.f,0.f}; acc2[0] = z; acc2[1] = z; }
  #pragma unroll
  for (int kt = 0; kt < 4; ++kt){
    i32x4 av = *(const i32x4*)(xb + col*FD + kt*32 + quad*8);  // A[m=col][k]
    #pragma unroll
    for (int ntl = 0; ntl < 2; ++ntl){
      // s_nop 1: VALU-write -> MFMA-read SrcA/B hazard; trailing nops: MFMA-write -> VALU-read
      asm volatile("s_nop 1\n\t"
                   "v_mfma_f32_16x16x32_bf16 %0, %1, %2, %0\n\t"
                   "s_nop 7\n\t"
                   "s_nop 7"
                   : "+v"(acc2[ntl]) : "v"(av), "v"(bfru[ntl][kt]));
    }
  }
  if (FP32){
    float* o = (float*)out_;
    #pragma unroll
    for (int ntl = 0; ntl < 2; ++ntl){
      const int n0 = (wv*2 + ntl)*16 + col;
      #pragma unroll
      for (int r = 0; r < 4; ++r)
        __builtin_nontemporal_store(fmaxf(acc2[ntl][r], 0.f),
                                    &o[(size_t)(pbase + quad*4 + r)*FD + n0]);
    }
  } else {
    u16* o = (u16*)out_;
    #pragma unroll
    for (int ntl = 0; ntl < 2; ++ntl){
      const int n0 = (wv*2 + ntl)*16 + col;
      #pragma unroll
      for (int r = 0; r < 4; ++r)
        __builtin_nontemporal_store(f2bf(fmaxf(acc2[ntl][r], 0.f)),
                                    &o[(size_t)(pbase + quad*4 + r)*FD + n0]);
    }
  }
}

__global__ __launch_bounds__(256) void fused(const void* __restrict__ xs, const void* __restrict__ xn,
                                             const float* __restrict__ wa, const int* __restrict__ flag,
                                             const u16* __restrict__ wpk, void* __restrict__ out_){
  __shared__ u16 xb[16*FD];   // 4 KB: 16 xbar rows, bf16
  if (flag[0]) fused_body<true >(xs, xn, wa, wpk, out_, xb);
  else         fused_body<false>(xs, xn, wa, wpk, out_, xb);
}

extern "C" void kernel_launch(void* const* d_in, const int* in_sizes, int n_in,
                              void* d_out, int out_size, void* d_ws, size_t ws_size,
                              hipStream_t stream){
  const void* x_self  = d_in[0];
  const void* x_neigh = d_in[1];
  const void* w_feat  = d_in[2];
  const void* a_self  = d_in[3];
  const void* a_neigh = d_in[4];

  int*   flag = (int*)d_ws;                  // byte 0
  float* wa   = (float*)d_ws + 64;           // byte 256: 256 floats [wa_self | wa_neigh]
  u16*   wpk  = (u16*)d_ws + 1024;           // byte 2048: 2048 fragments x 8 u16 = 32 KB packed W

  prep <<<FD + 32,  64, 0, stream>>>(w_feat, a_self, a_neigh, (const u16*)x_self, wa, wpk, flag);
  fused<<<NPAIR/16, 256, 0, stream>>>(x_self, x_neigh, wa, flag, wpk, d_out);
}